// Round 4
// baseline (349.295 us; speedup 1.0000x reference)
//
#include <hip/hip_runtime.h>
#include <stdint.h>

// Problem constants (fixed by the reference).
#define B_TOTAL 16384
#define F 512
#define L 256
#define TB 32      // batch rows per block
#define LDP 72     // padded LDS row stride in f16 elems per 64-col section

typedef _Float16 half8 __attribute__((ext_vector_type(8)));
typedef float floatx4 __attribute__((ext_vector_type(4)));

// Fragment-ordered f16 weights: [which][wn][kt][nt][lane][8]
//   l = wn*64 + nt*16 + (lane&15),  k = kt*32 + (lane>>4)*8 + j
// A wave's B-fragment load for (kt,nt) is lanes 0..63 x 16B = 1024B contiguous.
// Static device buffer, rewritten every launch (same data -> graph-capture safe).
__device__ __align__(16) _Float16 g_wt2[2][4][16][4][64][8];

__global__ void wconv_kernel(const float* __restrict__ uW,
                             const float* __restrict__ iW) {
    int tid = blockIdx.x * blockDim.x + threadIdx.x;   // 0 .. 32767
    int which = tid >> 14;        // 16384 chunks of 8 per matrix
    int r = tid & 16383;
    int l = r >> 6;               // 0..255
    int kc = r & 63;              // k/8 : consecutive tid -> contiguous 32B reads
    const float* src = (which ? iW : uW) + l * F + kc * 8;
    float4 v0 = *(const float4*)(src);
    float4 v1 = *(const float4*)(src + 4);
    _Float16 h[8];
    h[0] = (_Float16)v0.x; h[1] = (_Float16)v0.y;
    h[2] = (_Float16)v0.z; h[3] = (_Float16)v0.w;
    h[4] = (_Float16)v1.x; h[5] = (_Float16)v1.y;
    h[6] = (_Float16)v1.z; h[7] = (_Float16)v1.w;
    int wn   = l >> 6;
    int nt   = (l >> 4) & 3;
    int l15  = l & 15;
    int kt   = kc >> 2;
    int quad = kc & 3;
    int lane = quad * 16 + l15;
    *(half8*)(&g_wt2[which][wn][kt][nt][lane][0]) = *(half8*)h;
}

__launch_bounds__(256, 2)
__global__ void fused_kernel(const int* __restrict__ x,
                             const float* __restrict__ ulook,
                             const float* __restrict__ ilook,
                             const float* __restrict__ ub,
                             const float* __restrict__ ib,
                             float* __restrict__ out) {
    // [pass][ks][row][64 cols + 8 pad]; stride 144B -> conflict-free b128 phases
    __shared__ _Float16 sA[2][8][TB][LDP];
    __shared__ float    sRed[TB];

    const int t = threadIdx.x;
    const int bbase = blockIdx.x * TB;

    if (t < TB) sRed[t] = 0.0f;

    // ---- stage: gather BOTH passes' feature rows, full row at once ----
    // thread t: row = t>>3, 8-float section g8 = t&7. Row indices come
    // straight from global x as one int2 (8 threads share each 8B segment,
    // hardware broadcast) -> no LDS round-trip, no barrier before staging.
    // All 32 float4 loads are independent and issue back-to-back.
    {
        const int arow = t >> 3;
        const int g8   = t & 7;
        const int2 rowpair = *(const int2*)(&x[(bbase + arow) * 2]);
        const float* srcU = ulook + (size_t)rowpair.x * F + g8 * 8;
        const float* srcI = ilook + (size_t)rowpair.y * F + g8 * 8;
        #pragma unroll
        for (int pass = 0; pass < 2; ++pass) {
            const float* src0 = pass ? srcI : srcU;
            #pragma unroll
            for (int ks = 0; ks < 8; ++ks) {
                const float* src = src0 + ks * 64;
                float4 v0 = *(const float4*)(src);
                float4 v1 = *(const float4*)(src + 4);
                _Float16 h[8];
                h[0] = (_Float16)v0.x; h[1] = (_Float16)v0.y;
                h[2] = (_Float16)v0.z; h[3] = (_Float16)v0.w;
                h[4] = (_Float16)v1.x; h[5] = (_Float16)v1.y;
                h[6] = (_Float16)v1.z; h[7] = (_Float16)v1.w;
                *(half8*)(&sA[pass][ks][arow][g8 * 8]) = *(half8*)h;
            }
        }
    }
    __syncthreads();   // the ONLY barrier before the epilogue

    const int wave = t >> 6;          // wave owns L-chunk wn = wave (64 cols)
    const int lane = t & 63;
    const int l15  = lane & 15;
    const int quad = lane >> 4;

    floatx4 accU[2][4], accI[2][4];
    #pragma unroll
    for (int mt = 0; mt < 2; ++mt)
        #pragma unroll
        for (int nt = 0; nt < 4; ++nt) {
            floatx4 z = {0.f, 0.f, 0.f, 0.f};
            accU[mt][nt] = z; accI[mt][nt] = z;
        }

    // per-wave fragment base: g_wt2[pass][wave][kt][nt][lane][0]
    const _Float16* bw0 = &g_wt2[0][wave][0][0][lane][0];
    const _Float16* bw1 = &g_wt2[1][wave][0][0][lane][0];
    // strides in f16 elems: kt -> 4*64*8 = 2048 ; nt -> 64*8 = 512

    // ---- main K loop: NO barriers; compiler pipelines L2 loads + MFMA ----
    #pragma unroll 2
    for (int kt = 0; kt < 16; ++kt) {
        const int ks = kt >> 1;        // 64-col section in sA
        const int kk = kt & 1;         // which 32 within the section

        half8 aU[2], aI[2];
        #pragma unroll
        for (int mt = 0; mt < 2; ++mt) {
            aU[mt] = *(const half8*)(&sA[0][ks][mt * 16 + l15][kk * 32 + quad * 8]);
            aI[mt] = *(const half8*)(&sA[1][ks][mt * 16 + l15][kk * 32 + quad * 8]);
        }
        half8 bU[4], bI[4];
        #pragma unroll
        for (int nt = 0; nt < 4; ++nt) {
            bU[nt] = *(const half8*)(bw0 + kt * 2048 + nt * 512);
            bI[nt] = *(const half8*)(bw1 + kt * 2048 + nt * 512);
        }
        #pragma unroll
        for (int mt = 0; mt < 2; ++mt)
            #pragma unroll
            for (int nt = 0; nt < 4; ++nt) {
                accU[mt][nt] = __builtin_amdgcn_mfma_f32_16x16x32_f16(
                    aU[mt], bU[nt], accU[mt][nt], 0, 0, 0);
                accI[mt][nt] = __builtin_amdgcn_mfma_f32_16x16x32_f16(
                    aI[mt], bI[nt], accI[mt][nt], 0, 0, 0);
            }
    }

    // ---- epilogue: relu(U+bu)*relu(I+bi), reduce over L ----
    // C/D layout (16x16): col = lane&15 (n), row = quad*4 + r (m) — same
    // mapping the previous harness-verified kernel used.
    #pragma unroll
    for (int mt = 0; mt < 2; ++mt) {
        float partial[4] = {0.f, 0.f, 0.f, 0.f};
        #pragma unroll
        for (int nt = 0; nt < 4; ++nt) {
            int n = wave * 64 + nt * 16 + l15;
            float bu = ub[n];
            float bi = ib[n];
            #pragma unroll
            for (int r = 0; r < 4; ++r) {
                float vu = accU[mt][nt][r] + bu; vu = vu > 0.f ? vu : 0.f;
                float vi = accI[mt][nt][r] + bi; vi = vi > 0.f ? vi : 0.f;
                partial[r] += vu * vi;
            }
        }
        #pragma unroll
        for (int r = 0; r < 4; ++r) {
            float v = partial[r];
            v += __shfl_xor(v, 1);
            v += __shfl_xor(v, 2);
            v += __shfl_xor(v, 4);
            v += __shfl_xor(v, 8);
            if (l15 == 0)
                atomicAdd(&sRed[mt * 16 + quad * 4 + r], v);
        }
    }

    __syncthreads();
    if (t < TB) out[bbase + t] = sRed[t];
}

extern "C" void kernel_launch(void* const* d_in, const int* in_sizes, int n_in,
                              void* d_out, int out_size, void* d_ws, size_t ws_size,
                              hipStream_t stream) {
    const int*   x     = (const int*)d_in[0];
    const float* ulook = (const float*)d_in[1];
    const float* ilook = (const float*)d_in[2];
    const float* uW    = (const float*)d_in[3];
    const float* ub    = (const float*)d_in[4];
    const float* iW    = (const float*)d_in[5];
    const float* ib    = (const float*)d_in[6];
    float* out = (float*)d_out;

    wconv_kernel<<<128, 256, 0, stream>>>(uW, iW);
    fused_kernel<<<B_TOTAL / TB, 256, 0, stream>>>(x, ulook, ilook, ub, ib, out);
}

// Round 7
// 340.285 us; speedup vs baseline: 1.0265x; 1.0265x over previous
//
#include <hip/hip_runtime.h>
#include <stdint.h>

// Problem constants (fixed by the reference).
#define B_TOTAL 16384
#define F 512
#define L 256
#define TB 32      // batch rows per block
#define LDP 72     // padded LDS row stride in f16 elems per 64-col section

typedef _Float16 half8 __attribute__((ext_vector_type(8)));
typedef float floatx4 __attribute__((ext_vector_type(4)));

// Nontemporal 16B load: streaming use-once data must not evict the
// L2-resident weight table (round-4 theory: gather stream thrashes L2).
// NOTE: __builtin_nontemporal_load rejects HIP_vector_type (float4);
// it requires a plain scalar or clang ext_vector_type.
__device__ __forceinline__ floatx4 nt_load4(const float* p) {
    return __builtin_nontemporal_load((const floatx4*)p);
}

// Fragment-ordered f16 weights: [which][wn][kt][nt][lane][8]
//   l = wn*64 + nt*16 + (lane&15),  k = kt*32 + (lane>>4)*8 + j
// A wave's B-fragment load for (kt,nt) is lanes 0..63 x 16B = 1024B contiguous.
// Static device buffer, rewritten every launch (same data -> graph-capture safe).
__device__ __align__(16) _Float16 g_wt2[2][4][16][4][64][8];

__global__ void wconv_kernel(const float* __restrict__ uW,
                             const float* __restrict__ iW) {
    int tid = blockIdx.x * blockDim.x + threadIdx.x;   // 0 .. 32767
    int which = tid >> 14;        // 16384 chunks of 8 per matrix
    int r = tid & 16383;
    int l = r >> 6;               // 0..255
    int kc = r & 63;              // k/8 : consecutive tid -> contiguous 32B reads
    const float* src = (which ? iW : uW) + l * F + kc * 8;
    floatx4 v0 = nt_load4(src);
    floatx4 v1 = nt_load4(src + 4);
    _Float16 h[8];
    h[0] = (_Float16)v0.x; h[1] = (_Float16)v0.y;
    h[2] = (_Float16)v0.z; h[3] = (_Float16)v0.w;
    h[4] = (_Float16)v1.x; h[5] = (_Float16)v1.y;
    h[6] = (_Float16)v1.z; h[7] = (_Float16)v1.w;
    int wn   = l >> 6;
    int nt   = (l >> 4) & 3;
    int l15  = l & 15;
    int kt   = kc >> 2;
    int quad = kc & 3;
    int lane = quad * 16 + l15;
    *(half8*)(&g_wt2[which][wn][kt][nt][lane][0]) = *(half8*)h;
}

__launch_bounds__(256, 2)
__global__ void fused_kernel(const int* __restrict__ x,
                             const float* __restrict__ ulook,
                             const float* __restrict__ ilook,
                             const float* __restrict__ ub,
                             const float* __restrict__ ib,
                             float* __restrict__ out) {
    // [pass][ks][row][64 cols + 8 pad]; stride 144B -> conflict-free b128 phases
    __shared__ _Float16 sA[2][8][TB][LDP];
    __shared__ float    sRed[TB];

    const int t = threadIdx.x;
    const int bbase = blockIdx.x * TB;

    if (t < TB) sRed[t] = 0.0f;

    // ---- stage: gather BOTH passes' feature rows, full row at once ----
    // thread t: row = t>>3, 8-float section g8 = t&7. Row indices come
    // straight from global x as one int2 (8 threads share each 8B segment,
    // hardware broadcast) -> no LDS round-trip, no barrier before staging.
    // All 32 float4 loads are independent, issue back-to-back, and are
    // NONTEMPORAL: use-once stream must not evict g_wt2 from L2.
    {
        const int arow = t >> 3;
        const int g8   = t & 7;
        const int2 rowpair = *(const int2*)(&x[(bbase + arow) * 2]);
        const float* srcU = ulook + (size_t)rowpair.x * F + g8 * 8;
        const float* srcI = ilook + (size_t)rowpair.y * F + g8 * 8;
        #pragma unroll
        for (int pass = 0; pass < 2; ++pass) {
            const float* src0 = pass ? srcI : srcU;
            #pragma unroll
            for (int ks = 0; ks < 8; ++ks) {
                const float* src = src0 + ks * 64;
                floatx4 v0 = nt_load4(src);
                floatx4 v1 = nt_load4(src + 4);
                _Float16 h[8];
                h[0] = (_Float16)v0.x; h[1] = (_Float16)v0.y;
                h[2] = (_Float16)v0.z; h[3] = (_Float16)v0.w;
                h[4] = (_Float16)v1.x; h[5] = (_Float16)v1.y;
                h[6] = (_Float16)v1.z; h[7] = (_Float16)v1.w;
                *(half8*)(&sA[pass][ks][arow][g8 * 8]) = *(half8*)h;
            }
        }
    }
    __syncthreads();   // the ONLY barrier before the epilogue

    const int wave = t >> 6;          // wave owns L-chunk wn = wave (64 cols)
    const int lane = t & 63;
    const int l15  = lane & 15;
    const int quad = lane >> 4;

    floatx4 accU[2][4], accI[2][4];
    #pragma unroll
    for (int mt = 0; mt < 2; ++mt)
        #pragma unroll
        for (int nt = 0; nt < 4; ++nt) {
            floatx4 z = {0.f, 0.f, 0.f, 0.f};
            accU[mt][nt] = z; accI[mt][nt] = z;
        }

    // per-wave fragment base: g_wt2[pass][wave][kt][nt][lane][0]
    const _Float16* bw0 = &g_wt2[0][wave][0][0][lane][0];
    const _Float16* bw1 = &g_wt2[1][wave][0][0][lane][0];
    // strides in f16 elems: kt -> 4*64*8 = 2048 ; nt -> 64*8 = 512

    // ---- main K loop: NO barriers. FULL unroll gives the scheduler a
    // 16-iteration window to hoist the L2 B-fragment loads ahead of their
    // MFMAs (all indices compile-time -> everything stays in registers).
    #pragma unroll
    for (int kt = 0; kt < 16; ++kt) {
        const int ks = kt >> 1;        // 64-col section in sA
        const int kk = kt & 1;         // which 32 within the section

        half8 aU[2], aI[2];
        #pragma unroll
        for (int mt = 0; mt < 2; ++mt) {
            aU[mt] = *(const half8*)(&sA[0][ks][mt * 16 + l15][kk * 32 + quad * 8]);
            aI[mt] = *(const half8*)(&sA[1][ks][mt * 16 + l15][kk * 32 + quad * 8]);
        }
        half8 bU[4], bI[4];
        #pragma unroll
        for (int nt = 0; nt < 4; ++nt) {
            bU[nt] = *(const half8*)(bw0 + kt * 2048 + nt * 512);
            bI[nt] = *(const half8*)(bw1 + kt * 2048 + nt * 512);
        }
        #pragma unroll
        for (int mt = 0; mt < 2; ++mt)
            #pragma unroll
            for (int nt = 0; nt < 4; ++nt) {
                accU[mt][nt] = __builtin_amdgcn_mfma_f32_16x16x32_f16(
                    aU[mt], bU[nt], accU[mt][nt], 0, 0, 0);
                accI[mt][nt] = __builtin_amdgcn_mfma_f32_16x16x32_f16(
                    aI[mt], bI[nt], accI[mt][nt], 0, 0, 0);
            }
    }

    // ---- epilogue: relu(U+bu)*relu(I+bi), reduce over L ----
    // C/D layout (16x16): col = lane&15 (n), row = quad*4 + r (m) — same
    // mapping the previous harness-verified kernel used.
    #pragma unroll
    for (int mt = 0; mt < 2; ++mt) {
        float partial[4] = {0.f, 0.f, 0.f, 0.f};
        #pragma unroll
        for (int nt = 0; nt < 4; ++nt) {
            int n = wave * 64 + nt * 16 + l15;
            float bu = ub[n];
            float bi = ib[n];
            #pragma unroll
            for (int r = 0; r < 4; ++r) {
                float vu = accU[mt][nt][r] + bu; vu = vu > 0.f ? vu : 0.f;
                float vi = accI[mt][nt][r] + bi; vi = vi > 0.f ? vi : 0.f;
                partial[r] += vu * vi;
            }
        }
        #pragma unroll
        for (int r = 0; r < 4; ++r) {
            float v = partial[r];
            v += __shfl_xor(v, 1);
            v += __shfl_xor(v, 2);
            v += __shfl_xor(v, 4);
            v += __shfl_xor(v, 8);
            if (l15 == 0)
                atomicAdd(&sRed[mt * 16 + quad * 4 + r], v);
        }
    }

    __syncthreads();
    if (t < TB) out[bbase + t] = sRed[t];
}

extern "C" void kernel_launch(void* const* d_in, const int* in_sizes, int n_in,
                              void* d_out, int out_size, void* d_ws, size_t ws_size,
                              hipStream_t stream) {
    const int*   x     = (const int*)d_in[0];
    const float* ulook = (const float*)d_in[1];
    const float* ilook = (const float*)d_in[2];
    const float* uW    = (const float*)d_in[3];
    const float* ub    = (const float*)d_in[4];
    const float* iW    = (const float*)d_in[5];
    const float* ib    = (const float*)d_in[6];
    float* out = (float*)d_out;

    wconv_kernel<<<256, 128, 0, stream>>>(uW, iW);
    fused_kernel<<<B_TOTAL / TB, 256, 0, stream>>>(x, ulook, ilook, ub, ib, out);
}